// Round 10
// baseline (39.852 us; speedup 1.0000x reference)
//
#include <hip/hip_runtime.h>

// UVFA_text: B=256, M2=100, SV=OV=32, R=128, L=12, V=1000, E=64
// out[b,p] = sum_k relu(h2[p,k]+bs2[k]) * u[k] + bs3.w
//   h2[p,k] = relu(base_s + Ws1_pos[p]) @ Ws2[:,k]
//   w = obj_mlp(b) * lstm_h(b);  u[k] = Ws3[k,:] . w
// r10: (a) waves_per_eu pinned 4,4 -> full 128-VGPR budget, no spill;
//      (b) pre-pack kernel: Whh/Wih -> f16 transposed, Ws2 -> u32 pairs
//          (A/B fragments load as contiguous dwordx4, L2 traffic halved);
//      (c) h1P stride 68 -> aligned ds_read_b128 in P8.

#define B_   256
#define M2_  100
#define R_   128
#define L_   12
#define E_   64
#define NT   1024

typedef _Float16 half2v __attribute__((ext_vector_type(2)));
typedef _Float16 f16x8  __attribute__((ext_vector_type(8)));
typedef float    f32x4  __attribute__((ext_vector_type(4)));

__device__ __forceinline__ float sigf(float x) { return 1.f / (1.f + expf(-x)); }

__device__ __forceinline__ uint pk16(float a, float b) {
    half2v h; h.x = (_Float16)a; h.y = (_Float16)b;
    return __builtin_bit_cast(uint, h);
}

// ---- pack: WhhT16[c][r] (512x128 f16), WihT16[c][e] (512x64 f16), Ws2P u32 pairs ----
__global__ __launch_bounds__(256) void pack_kernel(
    const float* __restrict__ Whh, const float* __restrict__ Wih,
    const float* __restrict__ Ws2, void* __restrict__ wsv)
{
    _Float16* WhhT = (_Float16*)wsv;            // [512][128]
    _Float16* WihT = WhhT + 65536;              // [512][64]
    uint*     W2P  = (uint*)(WihT + 32768);     // [64][128]
    int g = blockIdx.x * 256 + threadIdx.x;
    if (g < 65536) {
        int r = g >> 9, c = g & 511;            // coalesced read
        WhhT[c * 128 + r] = (_Float16)Whh[r * 512 + c];
    } else if (g < 65536 + 32768) {
        int g2 = g - 65536;
        int e = g2 >> 9, c = g2 & 511;
        WihT[c * 64 + e] = (_Float16)Wih[e * 512 + c];
    } else if (g < 65536 + 32768 + 8192) {
        int g3 = g - 65536 - 32768;
        int jp = g3 >> 7, kk = g3 & 127;
        W2P[g3] = pk16(Ws2[(2 * jp) * R_ + kk], Ws2[(2 * jp + 1) * R_ + kk]);
    }
}

__global__ __launch_bounds__(NT) __attribute__((amdgpu_waves_per_eu(4, 4)))
void uvfa_kernel(
    const int* __restrict__ state, const int* __restrict__ obj, const int* __restrict__ text,
    const float* __restrict__ Ws1, const float* __restrict__ bs1,
    const float* __restrict__ bs2, const float* __restrict__ Ws3, const float* __restrict__ bs3,
    const float* __restrict__ Wo1, const float* __restrict__ bo1,
    const float* __restrict__ Wo2, const float* __restrict__ bo2,
    const float* __restrict__ Wo3, const float* __restrict__ bo3,
    const float* __restrict__ emb, const float* __restrict__ b_lstm,
    const _Float16* __restrict__ WhhT, const _Float16* __restrict__ WihT,
    const uint* __restrict__ W2P,
    float* __restrict__ out)
{
    const int b   = blockIdx.x;
    const int tid = threadIdx.x;

    // U (64.3 KiB union):
    //  phase A: xw f32 [16][512] = U[0..8191]; xemb f32 [16][66] = U[8192..9247]
    //  phase B: Ws2P u32 [64][132] = U[0..8447]; h1P u32 [112][68] = U[8448..16063]
    __shared__ __align__(16) uint  U[16064];
    __shared__ __align__(16) float part[NT];
    __shared__ __align__(16) float hbuf[R_];
    __shared__ __align__(16) uint  hpair[R_ / 2];
    __shared__ __align__(16) float tmp[R_], tmp2[R_], wbuf[R_], ubuf[R_], bsbuf[R_];
    __shared__ float redw2[2][112];
    __shared__ int   idx_o[M2_], idx_s[M2_], tids[L_];
    __shared__ float c0s;

    float* xw   = (float*)U;            // [16][512]
    float* xemb = (float*)(U + 8192);   // [16][66], rows 12..15 zero

    const int lane = tid & 63;
    const int wv   = tid >> 6;          // 0..15
    const int m16  = lane & 15;
    const int kgrp = lane >> 4;         // 0..3

    // ---------- LSTM A-fragments: contiguous dwordx4 from WhhT16 ----------
    f16x8 af[2][4];
    #pragma unroll
    for (int tt = 0; tt < 2; ++tt) {
        int col = (2 * wv + tt) * 16 + m16;
        #pragma unroll
        for (int s = 0; s < 4; ++s)
            af[tt][s] = *(const f16x8*)&WhhT[col * 128 + s * 32 + kgrp * 8];
    }

    // ---------- P1: ids + init ----------
    if (tid < M2_) idx_o[tid] = obj[b * M2_ + tid];
    else if (tid >= 128 && tid < 128 + M2_) idx_s[tid - 128] = state[b * M2_ + tid - 128];
    else if (tid >= 256 && tid < 256 + L_) tids[tid - 256] = text[b * L_ + tid - 256];
    else if (tid >= 384 && tid < 448) hpair[tid - 384] = 0u;
    __syncthreads();
    if (tid < L_ * E_) xemb[(tid >> 6) * 66 + (tid & 63)] = emb[tids[tid >> 6] * E_ + (tid & 63)];
    else if (tid < L_ * E_ + 264) ((float*)(U + 8192 + 792))[tid - L_ * E_] = 0.f;  // rows 12..15
    __syncthreads();

    // ---------- P2: xw = b_lstm + x @ Wih via MFMA ----------
    {
        f16x8 ax[2];
        #pragma unroll
        for (int s = 0; s < 2; ++s) {
            #pragma unroll
            for (int e = 0; e < 8; ++e)
                ax[s][e] = (_Float16)xemb[m16 * 66 + s * 32 + kgrp * 8 + e];
        }
        #pragma unroll
        for (int h = 0; h < 2; ++h) {
            int col = (wv * 2 + h) * 16 + m16;
            float bl = b_lstm[col];
            f32x4 acc = { bl, bl, bl, bl };
            #pragma unroll
            for (int s = 0; s < 2; ++s) {
                f16x8 bx = *(const f16x8*)&WihT[col * 64 + s * 32 + kgrp * 8];
                acc = __builtin_amdgcn_mfma_f32_16x16x32_f16(ax[s], bx, acc, 0, 0, 0);
            }
            if (kgrp < 3) {       // rows t = kgrp*4+r < 12
                #pragma unroll
                for (int r = 0; r < 4; ++r)
                    xw[(kgrp * 4 + r) * 512 + col] = acc[r];
            }
        }
    }
    __syncthreads();

    // ---------- LSTM: 12 steps (validated r8/r9) ----------
    float cst = 0.f;
    for (int t = 0; t < L_; ++t) {
        f16x8 bf[4];
        #pragma unroll
        for (int s = 0; s < 4; ++s) {
            uint4 hb = *(const uint4*)&hpair[s * 16 + kgrp * 4];
            bf[s] = __builtin_bit_cast(f16x8, hb);
        }
        #pragma unroll
        for (int tt = 0; tt < 2; ++tt) {
            int colb = (2 * wv + tt) * 16 + kgrp * 4;
            f32x4 acc = *(const f32x4*)&xw[t * 512 + colb];
            #pragma unroll
            for (int s = 0; s < 4; ++s)
                acc = __builtin_amdgcn_mfma_f32_16x16x32_f16(af[tt][s], bf[s], acc, 0, 0, 0);
            if (m16 == 0) {
                part[colb + 0] = acc[0];
                part[colb + 1] = acc[1];
                part[colb + 2] = acc[2];
                part[colb + 3] = acc[3];
            }
        }
        __syncthreads();
        if (tid < R_) {
            float gi = part[tid], gf = part[R_ + tid], gg = part[2 * R_ + tid], go = part[3 * R_ + tid];
            cst = sigf(gf) * cst + sigf(gi) * tanhf(gg);
            float hn = sigf(go) * tanhf(cst);
            hbuf[tid] = hn;
            float hs = __shfl_down(hn, 1, 64);
            if (!(tid & 1)) hpair[tid >> 1] = pk16(hn, hs);
        }
        __syncthreads();
    }

    // ---------- stage Ws2P [64][132] via uint4 copy (xw dead) ----------
    {
        const uint4* src = (const uint4*)W2P;
        #pragma unroll
        for (int idx = tid; idx < 2048; idx += NT) {    // 2 iters
            uint4 v = src[idx];
            int jp = idx >> 5, kq = idx & 31;
            *(uint4*)&U[jp * 132 + kq * 4] = v;
        }
    }

    // ---------- P4: object MLP ----------
    const int k = tid & 127, qq = tid >> 7;   // qq 0..7
    {
        float acc = 0.f;
        int c0i = qq * 13, c1i = c0i + 13 < M2_ ? c0i + 13 : M2_;
        for (int c = c0i; c < c1i; ++c)
            acc += Wo1[(c * 32 + idx_o[c]) * R_ + k];
        part[qq * R_ + k] = acc;
    }
    __syncthreads();
    if (tid < R_) {
        float a = bo1[tid];
        #pragma unroll
        for (int q8 = 0; q8 < 8; ++q8) a += part[q8 * R_ + tid];
        tmp[tid] = fmaxf(a, 0.f);
    }
    __syncthreads();
    {
        float s0 = 0.f, s1 = 0.f, s2 = 0.f, s3 = 0.f;
        int j0 = qq * 16;
        #pragma unroll
        for (int j = 0; j < 16; j += 4) {
            s0 = fmaf(tmp[j0 + j + 0], Wo2[(j0 + j + 0) * R_ + k], s0);
            s1 = fmaf(tmp[j0 + j + 1], Wo2[(j0 + j + 1) * R_ + k], s1);
            s2 = fmaf(tmp[j0 + j + 2], Wo2[(j0 + j + 2) * R_ + k], s2);
            s3 = fmaf(tmp[j0 + j + 3], Wo2[(j0 + j + 3) * R_ + k], s3);
        }
        part[qq * R_ + k] = (s0 + s1) + (s2 + s3);
    }
    __syncthreads();
    if (tid < R_) {
        float a = bo2[tid];
        #pragma unroll
        for (int q8 = 0; q8 < 8; ++q8) a += part[q8 * R_ + tid];
        tmp2[tid] = fmaxf(a, 0.f);
    }
    __syncthreads();
    {
        float s0 = 0.f, s1 = 0.f, s2 = 0.f, s3 = 0.f;
        int j0 = qq * 16;
        #pragma unroll
        for (int j = 0; j < 16; j += 4) {
            s0 = fmaf(tmp2[j0 + j + 0], Wo3[(j0 + j + 0) * R_ + k], s0);
            s1 = fmaf(tmp2[j0 + j + 1], Wo3[(j0 + j + 1) * R_ + k], s1);
            s2 = fmaf(tmp2[j0 + j + 2], Wo3[(j0 + j + 2) * R_ + k], s2);
            s3 = fmaf(tmp2[j0 + j + 3], Wo3[(j0 + j + 3) * R_ + k], s3);
        }
        part[qq * R_ + k] = (s0 + s1) + (s2 + s3);
    }
    __syncthreads();
    if (tid < R_) {
        float a = bo3[tid];
        #pragma unroll
        for (int q8 = 0; q8 < 8; ++q8) a += part[q8 * R_ + tid];
        wbuf[tid] = a * hbuf[tid];
    }
    __syncthreads();

    // ---------- P5: u = Ws3 @ w ; c0 = bs3 . w ----------
    {
        float s0 = 0.f, s1 = 0.f, s2 = 0.f, s3 = 0.f;
        int j0 = qq * 16;
        const float4* w3 = reinterpret_cast<const float4*>(&Ws3[k * R_ + j0]);
        #pragma unroll
        for (int jj = 0; jj < 4; ++jj) {
            float4 v = w3[jj];
            s0 = fmaf(v.x, wbuf[j0 + jj * 4 + 0], s0);
            s1 = fmaf(v.y, wbuf[j0 + jj * 4 + 1], s1);
            s2 = fmaf(v.z, wbuf[j0 + jj * 4 + 2], s2);
            s3 = fmaf(v.w, wbuf[j0 + jj * 4 + 3], s3);
        }
        part[qq * R_ + k] = (s0 + s1) + (s2 + s3);
    }
    if (tid >= 960) {
        int j = tid - 960;
        float s = bs3[j] * wbuf[j] + bs3[j + 64] * wbuf[j + 64];
        s += __shfl_down(s, 32, 64);
        s += __shfl_down(s, 16, 64);
        s += __shfl_down(s, 8, 64);
        s += __shfl_down(s, 4, 64);
        s += __shfl_down(s, 2, 64);
        s += __shfl_down(s, 1, 64);
        if (j == 0) c0s = s;
    }
    __syncthreads();
    if (tid < R_) {
        float a = 0.f;
        #pragma unroll
        for (int q8 = 0; q8 < 8; ++q8) a += part[q8 * R_ + tid];
        ubuf[tid] = a;
    }
    __syncthreads();

    // ---------- P6: base_s gather ----------
    {
        float acc = 0.f;
        int c0i = qq * 13, c1i = c0i + 13 < M2_ ? c0i + 13 : M2_;
        for (int c = c0i; c < c1i; ++c)
            acc += Ws1[(c * 33 + idx_s[c]) * R_ + k];
        part[qq * R_ + k] = acc;
    }
    __syncthreads();
    if (tid < R_) {
        float a = bs1[tid];
        #pragma unroll
        for (int q8 = 0; q8 < 8; ++q8) a += part[q8 * R_ + tid];
        bsbuf[tid] = a;
    }
    __syncthreads();

    // ---------- stage h1P [112][68] f16-pairs; zero rows 100..111 ----------
    #pragma unroll 4
    for (int pass = 0; pass < 13; ++pass) {
        int idx = pass * NT + tid;
        if (idx < M2_ * R_) {
            int j = idx & 127, p = idx >> 7;
            float v = fmaxf(bsbuf[j] + Ws1[(p * 33 + 32) * R_ + j], 0.f);
            float v2 = __shfl_down(v, 1, 64);
            if (!(j & 1)) U[8448 + p * 68 + (j >> 1)] = pk16(v, v2);
        }
    }
    if (tid < 816) U[8448 + 6800 + tid] = 0u;   // rows 100..111
    __syncthreads();

    // ---------- P8: h2 = h1 @ Ws2 via MFMA; wave = (mtile, nhalf) ----------
    if (wv < 14) {
        const int mtile = wv >> 1, nhalf = wv & 1;
        const uint* Ap = U + 8448 + (mtile * 16 + m16) * 68;
        f16x8 A[4];
        #pragma unroll
        for (int s = 0; s < 4; ++s)
            A[s] = __builtin_bit_cast(f16x8, *(const uint4*)&Ap[s * 16 + kgrp * 4]);
        f32x4 acc[4] = { {0,0,0,0}, {0,0,0,0}, {0,0,0,0}, {0,0,0,0} };
        #pragma unroll
        for (int nt = 0; nt < 4; ++nt) {
            int ko = (nhalf * 4 + nt) * 16 + m16;
            #pragma unroll
            for (int s = 0; s < 4; ++s) {
                const uint* Bp = U + (s * 16 + kgrp * 4) * 132 + ko;
                uint4 bv = { Bp[0], Bp[132], Bp[264], Bp[396] };
                acc[nt] = __builtin_amdgcn_mfma_f32_16x16x32_f16(
                    A[s], __builtin_bit_cast(f16x8, bv), acc[nt], 0, 0, 0);
            }
        }
        float vs0 = 0.f, vs1 = 0.f, vs2 = 0.f, vs3 = 0.f;
        #pragma unroll
        for (int nt = 0; nt < 4; ++nt) {
            int ko = (nhalf * 4 + nt) * 16 + m16;
            float bb = bs2[ko], uu = ubuf[ko];
            vs0 = fmaf(fmaxf(acc[nt][0] + bb, 0.f), uu, vs0);
            vs1 = fmaf(fmaxf(acc[nt][1] + bb, 0.f), uu, vs1);
            vs2 = fmaf(fmaxf(acc[nt][2] + bb, 0.f), uu, vs2);
            vs3 = fmaf(fmaxf(acc[nt][3] + bb, 0.f), uu, vs3);
        }
        vs0 += __shfl_xor(vs0, 1, 64); vs0 += __shfl_xor(vs0, 2, 64);
        vs0 += __shfl_xor(vs0, 4, 64); vs0 += __shfl_xor(vs0, 8, 64);
        vs1 += __shfl_xor(vs1, 1, 64); vs1 += __shfl_xor(vs1, 2, 64);
        vs1 += __shfl_xor(vs1, 4, 64); vs1 += __shfl_xor(vs1, 8, 64);
        vs2 += __shfl_xor(vs2, 1, 64); vs2 += __shfl_xor(vs2, 2, 64);
        vs2 += __shfl_xor(vs2, 4, 64); vs2 += __shfl_xor(vs2, 8, 64);
        vs3 += __shfl_xor(vs3, 1, 64); vs3 += __shfl_xor(vs3, 2, 64);
        vs3 += __shfl_xor(vs3, 4, 64); vs3 += __shfl_xor(vs3, 8, 64);
        if (m16 == 0) {
            int pr = mtile * 16 + kgrp * 4;
            redw2[nhalf][pr + 0] = vs0;
            redw2[nhalf][pr + 1] = vs1;
            redw2[nhalf][pr + 2] = vs2;
            redw2[nhalf][pr + 3] = vs3;
        }
    }
    __syncthreads();

    // ---------- final ----------
    if (tid < M2_)
        out[b * M2_ + tid] = c0s + redw2[0][tid] + redw2[1][tid];
}

extern "C" void kernel_launch(void* const* d_in, const int* in_sizes, int n_in,
                              void* d_out, int out_size, void* d_ws, size_t ws_size,
                              hipStream_t stream) {
    const int*   state  = (const int*)d_in[0];
    const int*   obj    = (const int*)d_in[1];
    const int*   text   = (const int*)d_in[2];
    const float* Ws1    = (const float*)d_in[3];
    const float* bs1    = (const float*)d_in[4];
    const float* Ws2    = (const float*)d_in[5];
    const float* bs2    = (const float*)d_in[6];
    const float* Ws3    = (const float*)d_in[7];
    const float* bs3    = (const float*)d_in[8];
    const float* Wo1    = (const float*)d_in[9];
    const float* bo1    = (const float*)d_in[10];
    const float* Wo2    = (const float*)d_in[11];
    const float* bo2    = (const float*)d_in[12];
    const float* Wo3    = (const float*)d_in[13];
    const float* bo3    = (const float*)d_in[14];
    const float* emb    = (const float*)d_in[15];
    const float* Wih    = (const float*)d_in[16];
    const float* Whh    = (const float*)d_in[17];
    const float* b_lstm = (const float*)d_in[18];
    float* out = (float*)d_out;

    _Float16* WhhT = (_Float16*)d_ws;           // [512][128]
    _Float16* WihT = WhhT + 65536;              // [512][64]
    uint*     W2P  = (uint*)(WihT + 32768);     // [64][128]

    hipLaunchKernelGGL(pack_kernel, dim3(416), dim3(256), 0, stream, Whh, Wih, Ws2, d_ws);
    hipLaunchKernelGGL(uvfa_kernel, dim3(B_), dim3(NT), 0, stream,
                       state, obj, text, Ws1, bs1, bs2, Ws3, bs3,
                       Wo1, bo1, Wo2, bo2, Wo3, bo3, emb, b_lstm,
                       WhhT, WihT, W2P, out);
}